// Round 12
// baseline (560.304 us; speedup 1.0000x reference)
//
#include <hip/hip_runtime.h>
#include <hip/hip_cooperative_groups.h>
#include <hip/hip_fp16.h>
#include <math.h>

namespace cg = cooperative_groups;

#define TAU_INV 5.0f      // 1 / 0.2
#define LOG2E   1.4426950408889634f
#define NTHR    512

typedef _Float16 half2v __attribute__((ext_vector_type(2)));
typedef _Float16 f16x8  __attribute__((ext_vector_type(8)));
typedef float    f32x4  __attribute__((ext_vector_type(4)));
typedef float    fv4    __attribute__((ext_vector_type(4)));

__device__ __forceinline__ float fast_exp2(float x) { return __builtin_amdgcn_exp2f(x); }
__device__ __forceinline__ float fast_log2(float x) { return __builtin_amdgcn_logf(x); }

__device__ __forceinline__ double exp_double(float z) {
    float y = z * LOG2E;
    float n = rintf(y);
    float r = y - n;
    float f = fast_exp2(r);
    long long e = (long long)n + 1023;
    if (e < 1)    e = 1;
    if (e > 2046) e = 2046;
    double scale = __longlong_as_double(e << 52);
    return (double)f * scale;
}

__device__ __forceinline__ float log2_of_double(double v) {
    unsigned long long b = __double_as_longlong(v);
    int ex = (int)((b >> 52) & 0x7FFULL) - 1023;
    double m = __longlong_as_double((b & 0xFFFFFFFFFFFFFULL) | 0x3FF0000000000000ULL);
    return (float)ex + fast_log2((float)m);
}

// ===========================================================================
// FUSED persistent kernel (cooperative launch; grid sized by occupancy API).
// P0 convert W + zero seg_sumd | P1 MFMA GEMM (R8 body, tile queue)
// P2 edge dot + seg-sum (R4 body) | P3 normalize (R3 body)
// ctrl[0] = gemm tile queue (host memsets to 0 each launch).
// ===========================================================================
__global__ __launch_bounds__(NTHR) void fused_pipeline(
    const float* __restrict__ Xu, const float* __restrict__ Xi,
    const float* __restrict__ Wq, const float* __restrict__ bq,
    const float* __restrict__ Wk, const float* __restrict__ bk,
    const int* __restrict__ rows, const int* __restrict__ cols,
    const float* __restrict__ noise_ui, const float* __restrict__ noise_iu,
    float* __restrict__ out, __half* __restrict__ QK,
    double* __restrict__ seg_sumd,
    _Float16* __restrict__ Wt_hi, _Float16* __restrict__ Wt_lo,
    int* __restrict__ ctrl,
    int U, int I, int E)
{
    cg::grid_group grid = cg::this_grid();
    const int tid    = threadIdx.x;
    const int bid    = blockIdx.x;
    const int stride = gridDim.x * NTHR;
    const int nseg   = U + I;
    const int NT     = nseg;

    __shared__ _Float16 Ah[64][72];
    __shared__ _Float16 Al[64][72];
    __shared__ int tile_s;

    // ================= PHASE 0: convert W + zero seg_sumd =================
    for (int t = bid * NTHR + tid; t < 65536; t += stride) {
        int n = t >> 8;
        int k = t & 255;
        float x = (n < 128) ? Wq[k * 128 + n] : Wk[k * 128 + (n - 128)];
        _Float16 hi = (_Float16)x;
        _Float16 lo = (_Float16)(x - (float)hi);
        Wt_hi[n * 256 + k] = hi;
        Wt_lo[n * 256 + k] = lo;
    }
    for (int i = bid * NTHR + tid; i < nseg; i += stride) seg_sumd[i] = 0.0;
    grid.sync();

    // ================= PHASE 1: MFMA GEMM (R8 body, tile queue) ============
    {
        const int l  = tid & 63;
        const int lr = l & 15;
        const int kc = l >> 4;
        const int n0 = (tid >> 6) * 32;      // wave 0..7 -> 32-col slice
        const int sr = tid >> 3;             // staging row 0..63
        const int sk = (tid & 7) * 8;        // staging half-offset
        const int ntiles = (nseg + 63) / 64;

        for (;;) {
            if (tid == 0) tile_s = atomicAdd(&ctrl[0], 1);
            __syncthreads();
            const int tile = tile_s;
            if (tile >= ntiles) break;
            const int row0 = tile * 64;

            f32x4 acc[4][2];
#pragma unroll
            for (int i = 0; i < 4; ++i)
#pragma unroll
                for (int j = 0; j < 2; ++j)
                    acc[i][j] = (f32x4){0.f, 0.f, 0.f, 0.f};

            const float* Xrow = nullptr;
            {
                int gr = row0 + sr;
                if (gr < U)       Xrow = &Xu[(size_t)gr * 256];
                else if (gr < NT) Xrow = &Xi[(size_t)(gr - U) * 256];
            }

            for (int k0 = 0; k0 < 256; k0 += 64) {
                {
                    fv4 v0, v1;
                    if (Xrow) {
                        v0 = __builtin_nontemporal_load((const fv4*)(Xrow + k0 + sk));
                        v1 = __builtin_nontemporal_load((const fv4*)(Xrow + k0 + sk + 4));
                    } else {
                        v0 = v1 = (fv4){0.f, 0.f, 0.f, 0.f};
                    }
                    float x[8] = {v0.x, v0.y, v0.z, v0.w, v1.x, v1.y, v1.z, v1.w};
                    _Float16 hi[8], lo[8];
#pragma unroll
                    for (int q = 0; q < 8; ++q) {
                        hi[q] = (_Float16)x[q];
                        lo[q] = (_Float16)(x[q] - (float)hi[q]);
                    }
                    *(f16x8*)&Ah[sr][sk] = *(const f16x8*)&hi[0];
                    *(f16x8*)&Al[sr][sk] = *(const f16x8*)&lo[0];
                }
                __syncthreads();

#pragma unroll
                for (int kk = 0; kk < 2; ++kk) {
                    const int kof = kk * 32 + kc * 8;
                    f16x8 ah[4], al[4];
#pragma unroll
                    for (int i = 0; i < 4; ++i) {
                        ah[i] = *(const f16x8*)&Ah[i * 16 + lr][kof];
                        al[i] = *(const f16x8*)&Al[i * 16 + lr][kof];
                    }
#pragma unroll
                    for (int j = 0; j < 2; ++j) {
                        const size_t wo = (size_t)(n0 + j * 16 + lr) * 256 + k0 + kof;
                        f16x8 bh = *(const f16x8*)&Wt_hi[wo];
                        f16x8 bl = *(const f16x8*)&Wt_lo[wo];
#pragma unroll
                        for (int i = 0; i < 4; ++i) {
                            acc[i][j] = __builtin_amdgcn_mfma_f32_16x16x32_f16(ah[i], bh, acc[i][j], 0, 0, 0);
                            acc[i][j] = __builtin_amdgcn_mfma_f32_16x16x32_f16(al[i], bh, acc[i][j], 0, 0, 0);
                            acc[i][j] = __builtin_amdgcn_mfma_f32_16x16x32_f16(ah[i], bl, acc[i][j], 0, 0, 0);
                        }
                    }
                }
                __syncthreads();
            }

            float bias[2];
#pragma unroll
            for (int j = 0; j < 2; ++j) {
                int col = n0 + j * 16 + lr;
                bias[j] = (col < 128) ? bq[col] : bk[col - 128];
            }
#pragma unroll
            for (int i = 0; i < 4; ++i) {
#pragma unroll
                for (int q = 0; q < 4; ++q) {
                    int gr = row0 + i * 16 + kc * 4 + q;
                    if (gr < NT) {
#pragma unroll
                        for (int j = 0; j < 2; ++j) {
                            int col = n0 + j * 16 + lr;
                            QK[(size_t)gr * 256 + col] = __float2half_rn(acc[i][j][q] + bias[j]);
                        }
                    }
                }
            }
            __syncthreads();   // protect Ah/Al + tile_s before next pop
        }
    }
    grid.sync();

    // ================= PHASE 2: edge dot + seg-sum (R4 body) ===============
    {
        const int hl = tid & 7;
        const long long total = (long long)E * 8;
        for (long long gt = (long long)bid * NTHR + tid; gt < total; gt += stride) {
            const int eid = (int)(gt >> 3);

            const int r = __builtin_nontemporal_load(&rows[eid]);
            const int c = __builtin_nontemporal_load(&cols[eid]);
            const __half* urow = QK + (size_t)r * 256;
            const __half* irow = QK + (size_t)(U + c) * 256;

            const uint4 qu0 = *(const uint4*)(urow + hl * 16);
            const uint4 qu1 = *(const uint4*)(urow + hl * 16 + 8);
            const uint4 ku0 = *(const uint4*)(urow + 128 + hl * 16);
            const uint4 ku1 = *(const uint4*)(urow + 128 + hl * 16 + 8);
            const uint4 qi0 = *(const uint4*)(irow + hl * 16);
            const uint4 qi1 = *(const uint4*)(irow + hl * 16 + 8);
            const uint4 ki0 = *(const uint4*)(irow + 128 + hl * 16);
            const uint4 ki1 = *(const uint4*)(irow + 128 + hl * 16 + 8);

            float d0 = 0.0f, d1 = 0.0f;
            {
                const half2v* a0 = (const half2v*)&qu0;
                const half2v* b0 = (const half2v*)&ki0;
                const half2v* a1 = (const half2v*)&qi0;
                const half2v* b1 = (const half2v*)&ku0;
#pragma unroll
                for (int t = 0; t < 4; ++t) {
                    d0 = __builtin_amdgcn_fdot2(a0[t], b0[t], d0, false);
                    d1 = __builtin_amdgcn_fdot2(a1[t], b1[t], d1, false);
                }
                const half2v* a0b = (const half2v*)&qu1;
                const half2v* b0b = (const half2v*)&ki1;
                const half2v* a1b = (const half2v*)&qi1;
                const half2v* b1b = (const half2v*)&ku1;
#pragma unroll
                for (int t = 0; t < 4; ++t) {
                    d0 = __builtin_amdgcn_fdot2(a0b[t], b0b[t], d0, false);
                    d1 = __builtin_amdgcn_fdot2(a1b[t], b1b[t], d1, false);
                }
            }
            d0 += __shfl_xor(d0, 4);  d1 += __shfl_xor(d1, 4);
            d0 += __shfl_xor(d0, 2);  d1 += __shfl_xor(d1, 2);
            d0 += __shfl_xor(d0, 1);  d1 += __shfl_xor(d1, 1);

            if (hl < 2) {
                const int g  = hl;                  // 0 = ui, 1 = iu
                const float d  = g ? d1 : d0;
                const float nz = g ? __builtin_nontemporal_load(&noise_iu[eid])
                                   : __builtin_nontemporal_load(&noise_ui[eid]);
                const float zz = (d - __logf(-__logf(nz))) * TAU_INV;
                const int s  = g ? (U + c) : r;
                __builtin_nontemporal_store(zz, &out[(size_t)g * E + eid]);
                atomicAdd(&seg_sumd[s], exp_double(zz));
            }
        }
    }
    grid.sync();

    // ================= PHASE 3: normalize (R3 body) ========================
    if ((E & 1) == 0) {
        for (int p = bid * NTHR + tid; p < E; p += stride) {
            int i = p * 2;
            const bool iu  = (i >= E);
            const int base = iu ? (i - E) : i;
            const int off  = iu ? U : 0;
            const int* idx = iu ? cols : rows;
            int2 rc   = *(const int2*)&idx[base];
            float2 zz = *(const float2*)&out[i];
            float l0 = log2_of_double(seg_sumd[off + rc.x]);
            float l1 = log2_of_double(seg_sumd[off + rc.y]);
            float o0 = fast_exp2(zz.x * LOG2E - l0);
            float o1 = fast_exp2(zz.y * LOG2E - l1);
            *(float2*)&out[i] = make_float2(o0, o1);
        }
    } else {
        for (int i = bid * NTHR + tid; i < 2 * E; i += stride) {
            int s = (i < E) ? rows[i] : (U + cols[i - E]);
            float l = log2_of_double(seg_sumd[s]);
            out[i] = fast_exp2(out[i] * LOG2E - l);
        }
    }
}

// ===========================================================================
// FALLBACK multi-dispatch pipeline (R8, proven 431 us) — used only when the
// cooperative launch is rejected by the runtime.
// ===========================================================================
__global__ __launch_bounds__(256) void convert_w(
    const float* __restrict__ Wq, const float* __restrict__ Wk,
    _Float16* __restrict__ Wt_hi, _Float16* __restrict__ Wt_lo,
    double* __restrict__ seg_sumd, int nseg)
{
    int t = blockIdx.x * 256 + threadIdx.x;
    int n = t >> 8;
    int k = t & 255;
    float x = (n < 128) ? Wq[k * 128 + n] : Wk[k * 128 + (n - 128)];
    _Float16 hi = (_Float16)x;
    _Float16 lo = (_Float16)(x - (float)hi);
    Wt_hi[n * 256 + k] = hi;
    Wt_lo[n * 256 + k] = lo;
    for (int i = t; i < nseg; i += 65536) seg_sumd[i] = 0.0;
}

__global__ __launch_bounds__(512) void gemm_qk_mfma(
    const float* __restrict__ Xu, const float* __restrict__ Xi,
    const _Float16* __restrict__ Wt_hi, const _Float16* __restrict__ Wt_lo,
    const float* __restrict__ bq, const float* __restrict__ bk,
    __half* __restrict__ QK, int U, int I)
{
    __shared__ _Float16 Ah[64][72];
    __shared__ _Float16 Al[64][72];

    const int tid  = threadIdx.x;
    const int row0 = blockIdx.x * 64;
    const int l    = tid & 63;
    const int lr   = l & 15;
    const int kc   = l >> 4;
    const int n0   = (tid >> 6) * 32;
    const int NT   = U + I;

    f32x4 acc[4][2];
#pragma unroll
    for (int i = 0; i < 4; ++i)
#pragma unroll
        for (int j = 0; j < 2; ++j)
            acc[i][j] = (f32x4){0.f, 0.f, 0.f, 0.f};

    const int sr = tid >> 3;
    const int sk = (tid & 7) * 8;
    const float* Xrow = nullptr;
    {
        int gr = row0 + sr;
        if (gr < U)       Xrow = &Xu[(size_t)gr * 256];
        else if (gr < NT) Xrow = &Xi[(size_t)(gr - U) * 256];
    }

    for (int k0 = 0; k0 < 256; k0 += 64) {
        {
            fv4 v0, v1;
            if (Xrow) {
                v0 = __builtin_nontemporal_load((const fv4*)(Xrow + k0 + sk));
                v1 = __builtin_nontemporal_load((const fv4*)(Xrow + k0 + sk + 4));
            } else {
                v0 = v1 = (fv4){0.f, 0.f, 0.f, 0.f};
            }
            float x[8] = {v0.x, v0.y, v0.z, v0.w, v1.x, v1.y, v1.z, v1.w};
            _Float16 hi[8], lo[8];
#pragma unroll
            for (int q = 0; q < 8; ++q) {
                hi[q] = (_Float16)x[q];
                lo[q] = (_Float16)(x[q] - (float)hi[q]);
            }
            *(f16x8*)&Ah[sr][sk] = *(const f16x8*)&hi[0];
            *(f16x8*)&Al[sr][sk] = *(const f16x8*)&lo[0];
        }
        __syncthreads();

#pragma unroll
        for (int kk = 0; kk < 2; ++kk) {
            const int kof = kk * 32 + kc * 8;
            f16x8 ah[4], al[4];
#pragma unroll
            for (int i = 0; i < 4; ++i) {
                ah[i] = *(const f16x8*)&Ah[i * 16 + lr][kof];
                al[i] = *(const f16x8*)&Al[i * 16 + lr][kof];
            }
#pragma unroll
            for (int j = 0; j < 2; ++j) {
                const size_t wo = (size_t)(n0 + j * 16 + lr) * 256 + k0 + kof;
                f16x8 bh = *(const f16x8*)&Wt_hi[wo];
                f16x8 bl = *(const f16x8*)&Wt_lo[wo];
#pragma unroll
                for (int i = 0; i < 4; ++i) {
                    acc[i][j] = __builtin_amdgcn_mfma_f32_16x16x32_f16(ah[i], bh, acc[i][j], 0, 0, 0);
                    acc[i][j] = __builtin_amdgcn_mfma_f32_16x16x32_f16(al[i], bh, acc[i][j], 0, 0, 0);
                    acc[i][j] = __builtin_amdgcn_mfma_f32_16x16x32_f16(ah[i], bl, acc[i][j], 0, 0, 0);
                }
            }
        }
        __syncthreads();
    }

    float bias[2];
#pragma unroll
    for (int j = 0; j < 2; ++j) {
        int col = n0 + j * 16 + lr;
        bias[j] = (col < 128) ? bq[col] : bk[col - 128];
    }
#pragma unroll
    for (int i = 0; i < 4; ++i) {
#pragma unroll
        for (int q = 0; q < 4; ++q) {
            int gr = row0 + i * 16 + kc * 4 + q;
            if (gr < NT) {
#pragma unroll
                for (int j = 0; j < 2; ++j) {
                    int col = n0 + j * 16 + lr;
                    QK[(size_t)gr * 256 + col] = __float2half_rn(acc[i][j][q] + bias[j]);
                }
            }
        }
    }
}

__global__ __launch_bounds__(256) void edge_w_both(
    const __half* __restrict__ QK,
    const int* __restrict__ rows, const int* __restrict__ cols,
    const float* __restrict__ noise_ui, const float* __restrict__ noise_iu,
    float* __restrict__ out, double* __restrict__ seg_sumd, int U, int E)
{
    const int gtid = blockIdx.x * 256 + threadIdx.x;
    const int eid  = gtid >> 3;
    if (eid >= E) return;
    const int hl = threadIdx.x & 7;

    const int r = __builtin_nontemporal_load(&rows[eid]);
    const int c = __builtin_nontemporal_load(&cols[eid]);
    const __half* urow = QK + (size_t)r * 256;
    const __half* irow = QK + (size_t)(U + c) * 256;

    const uint4 qu0 = *(const uint4*)(urow + hl * 16);
    const uint4 qu1 = *(const uint4*)(urow + hl * 16 + 8);
    const uint4 ku0 = *(const uint4*)(urow + 128 + hl * 16);
    const uint4 ku1 = *(const uint4*)(urow + 128 + hl * 16 + 8);
    const uint4 qi0 = *(const uint4*)(irow + hl * 16);
    const uint4 qi1 = *(const uint4*)(irow + hl * 16 + 8);
    const uint4 ki0 = *(const uint4*)(irow + 128 + hl * 16);
    const uint4 ki1 = *(const uint4*)(irow + 128 + hl * 16 + 8);

    float d0 = 0.0f, d1 = 0.0f;
    {
        const half2v* a0 = (const half2v*)&qu0;
        const half2v* b0 = (const half2v*)&ki0;
        const half2v* a1 = (const half2v*)&qi0;
        const half2v* b1 = (const half2v*)&ku0;
#pragma unroll
        for (int t = 0; t < 4; ++t) {
            d0 = __builtin_amdgcn_fdot2(a0[t], b0[t], d0, false);
            d1 = __builtin_amdgcn_fdot2(a1[t], b1[t], d1, false);
        }
        const half2v* a0b = (const half2v*)&qu1;
        const half2v* b0b = (const half2v*)&ki1;
        const half2v* a1b = (const half2v*)&qi1;
        const half2v* b1b = (const half2v*)&ku1;
#pragma unroll
        for (int t = 0; t < 4; ++t) {
            d0 = __builtin_amdgcn_fdot2(a0b[t], b0b[t], d0, false);
            d1 = __builtin_amdgcn_fdot2(a1b[t], b1b[t], d1, false);
        }
    }
    d0 += __shfl_xor(d0, 4);  d1 += __shfl_xor(d1, 4);
    d0 += __shfl_xor(d0, 2);  d1 += __shfl_xor(d1, 2);
    d0 += __shfl_xor(d0, 1);  d1 += __shfl_xor(d1, 1);

    if (hl < 2) {
        const int g  = hl;
        const float d  = g ? d1 : d0;
        const float nz = g ? __builtin_nontemporal_load(&noise_iu[eid])
                           : __builtin_nontemporal_load(&noise_ui[eid]);
        const float zz = (d - __logf(-__logf(nz))) * TAU_INV;
        const int s  = g ? (U + c) : r;
        __builtin_nontemporal_store(zz, &out[(size_t)g * E + eid]);
        atomicAdd(&seg_sumd[s], exp_double(zz));
    }
}

__global__ void edge_norm2v(float* __restrict__ z,
                            const int* __restrict__ rows, const int* __restrict__ cols,
                            const double* __restrict__ seg_sumd, int U, int E)
{
    int p = blockIdx.x * blockDim.x + threadIdx.x;
    int i = p * 2;
    if (i >= 2 * E) return;
    const bool iu  = (i >= E);
    const int base = iu ? (i - E) : i;
    const int off  = iu ? U : 0;
    const int* idx = iu ? cols : rows;
    int2 rc   = *(const int2*)&idx[base];
    float2 zz = *(const float2*)&z[i];
    float l0 = log2_of_double(seg_sumd[off + rc.x]);
    float l1 = log2_of_double(seg_sumd[off + rc.y]);
    float o0 = fast_exp2(zz.x * LOG2E - l0);
    float o1 = fast_exp2(zz.y * LOG2E - l1);
    *(float2*)&z[i] = make_float2(o0, o1);
}

__global__ void edge_norm2(float* __restrict__ z,
                           const int* __restrict__ rows, const int* __restrict__ cols,
                           const double* __restrict__ seg_sumd, int U, int E)
{
    int i = blockIdx.x * blockDim.x + threadIdx.x;
    if (i >= 2 * E) return;
    int s = (i < E) ? rows[i] : (U + cols[i - E]);
    float l = log2_of_double(seg_sumd[s]);
    z[i] = fast_exp2(z[i] * LOG2E - l);
}

// ---------------------------------------------------------------------------
extern "C" void kernel_launch(void* const* d_in, const int* in_sizes, int n_in,
                              void* d_out, int out_size, void* d_ws, size_t ws_size,
                              hipStream_t stream)
{
    const float* user_embed = (const float*)d_in[0];
    const float* item_embed = (const float*)d_in[1];
    const float* Wq = (const float*)d_in[2];
    const float* bq = (const float*)d_in[3];
    const float* Wk = (const float*)d_in[4];
    const float* bk = (const float*)d_in[5];
    const int* ui_rows    = (const int*)d_in[6];
    const int* ui_cols    = (const int*)d_in[7];
    const float* noise_ui = (const float*)d_in[8];
    const float* noise_iu = (const float*)d_in[9];

    const int H = in_sizes[3];           // 128
    const int D = in_sizes[2] / H;       // 256
    int U = in_sizes[0] / D;             // 50000
    int I = in_sizes[1] / D;             // 25000
    int E = in_sizes[6];                 // 1600000

    const int nseg = U + I;

    // workspace: QK fp16 (U+I)x256 | seg_sumd double | Wt_hi | Wt_lo | ctrl
    char* wsc = (char*)d_ws;
    __half* QK = (__half*)wsc;          wsc += (size_t)nseg * 256 * sizeof(__half);
    double* seg_sumd = (double*)wsc;    wsc += (size_t)nseg * sizeof(double);
    _Float16* Wt_hi = (_Float16*)wsc;   wsc += (size_t)256 * 256 * sizeof(_Float16);
    _Float16* Wt_lo = (_Float16*)wsc;   wsc += (size_t)256 * 256 * sizeof(_Float16);
    int* ctrl = (int*)wsc;              wsc += 4 * sizeof(int);

    float* out = (float*)d_out;

    // Grid size from the occupancy API (cached): guaranteed co-residency.
    static int s_nblk = 0;
    if (s_nblk == 0) {
        int dev = 0;
        (void)hipGetDevice(&dev);
        int ncu = 256;
        (void)hipDeviceGetAttribute(&ncu, hipDeviceAttributeMultiprocessorCount, dev);
        int perCU = 0;
        if (hipOccupancyMaxActiveBlocksPerMultiprocessor(&perCU, fused_pipeline, NTHR, 0)
                != hipSuccess || perCU < 1)
            perCU = 1;
        s_nblk = ncu * perCU;
    }

    (void)hipMemsetAsync(ctrl, 0, 4 * sizeof(int), stream);

    void* kargs[] = {
        (void*)&user_embed, (void*)&item_embed,
        (void*)&Wq, (void*)&bq, (void*)&Wk, (void*)&bk,
        (void*)&ui_rows, (void*)&ui_cols,
        (void*)&noise_ui, (void*)&noise_iu,
        (void*)&out, (void*)&QK, (void*)&seg_sumd,
        (void*)&Wt_hi, (void*)&Wt_lo, (void*)&ctrl,
        (void*)&U, (void*)&I, (void*)&E
    };

    hipError_t err = hipLaunchCooperativeKernel(
        fused_pipeline, dim3(s_nblk), dim3(NTHR), kargs, 0, stream);

    if (err != hipSuccess) {
        // ---- fallback: proven R8 multi-dispatch pipeline ----
        convert_w<<<256, 256, 0, stream>>>(Wq, Wk, Wt_hi, Wt_lo, seg_sumd, nseg);

        const int gblocks = (nseg + 63) / 64;
        gemm_qk_mfma<<<gblocks, 512, 0, stream>>>(user_embed, item_embed,
                                                  Wt_hi, Wt_lo, bq, bk, QK, U, I);

        const int eblocks = (int)(((long long)E * 8 + 255) / 256);
        edge_w_both<<<eblocks, 256, 0, stream>>>(QK, ui_rows, ui_cols,
                                                 noise_ui, noise_iu,
                                                 out, seg_sumd, U, E);

        if ((E & 1) == 0) {
            const int vblocks = (E + 255) / 256;
            edge_norm2v<<<vblocks, 256, 0, stream>>>(out, ui_rows, ui_cols,
                                                     seg_sumd, U, E);
        } else {
            const int sblocks = (2 * E + 255) / 256;
            edge_norm2<<<sblocks, 256, 0, stream>>>(out, ui_rows, ui_cols,
                                                    seg_sumd, U, E);
        }
    }
}

// Round 13
// 428.517 us; speedup vs baseline: 1.3075x; 1.3075x over previous
//
#include <hip/hip_runtime.h>
#include <hip/hip_fp16.h>
#include <math.h>

#define TAU_INV 5.0f      // 1 / 0.2
#define LOG2E   1.4426950408889634f

typedef _Float16 half2v __attribute__((ext_vector_type(2)));
typedef _Float16 f16x8  __attribute__((ext_vector_type(8)));
typedef float    f32x4  __attribute__((ext_vector_type(4)));
typedef float    fv4    __attribute__((ext_vector_type(4)));   // for nontemporal builtins

// raw gfx950 transcendentals: v_exp_f32 is 2^x, v_log_f32 is log2(x)
__device__ __forceinline__ float fast_exp2(float x) { return __builtin_amdgcn_exp2f(x); }
__device__ __forceinline__ float fast_log2(float x) { return __builtin_amdgcn_logf(x); }

// exp(z) as a double, via 2^n * exp2(r).  z in ~[-700, +700] is safe.
__device__ __forceinline__ double exp_double(float z) {
    float y = z * LOG2E;
    float n = rintf(y);
    float r = y - n;
    float f = fast_exp2(r);
    long long e = (long long)n + 1023;
    if (e < 1)    e = 1;
    if (e > 2046) e = 2046;
    double scale = __longlong_as_double(e << 52);
    return (double)f * scale;
}

// log2 of a positive normal double, to float precision.
__device__ __forceinline__ float log2_of_double(double v) {
    unsigned long long b = __double_as_longlong(v);
    int ex = (int)((b >> 52) & 0x7FFULL) - 1023;
    double m = __longlong_as_double((b & 0xFFFFFFFFFFFFFULL) | 0x3FF0000000000000ULL);
    return (float)ex + fast_log2((float)m);
}

// ---------------------------------------------------------------------------
// Build transposed fp16-SPLIT weight matrix:  Wt = [Wq | Wk]^T as [n=256][k=256]
// with hi = fp16(w), lo = fp16(w - hi).  Also zeroes seg_sumd (merged memset).
// ---------------------------------------------------------------------------
__global__ __launch_bounds__(256) void convert_w(
    const float* __restrict__ Wq, const float* __restrict__ Wk,
    _Float16* __restrict__ Wt_hi, _Float16* __restrict__ Wt_lo,
    double* __restrict__ seg_sumd, int nseg)
{
    int t = blockIdx.x * 256 + threadIdx.x;    // 65536 total
    int n = t >> 8;
    int k = t & 255;
    float x = (n < 128) ? Wq[k * 128 + n] : Wk[k * 128 + (n - 128)];
    _Float16 hi = (_Float16)x;
    _Float16 lo = (_Float16)(x - (float)hi);
    Wt_hi[n * 256 + k] = hi;
    Wt_lo[n * 256 + k] = lo;
    for (int i = t; i < nseg; i += 65536) seg_sumd[i] = 0.0;
}

// ---------------------------------------------------------------------------
// Compensated-fp16 MFMA GEMM (R8 structure — session optimum).
// D = Xhi*Whi + Xlo*Whi + Xhi*Wlo (f32 accum) == fp32 GEMM to ~2^-22.
// 512-thread blocks, 8 waves, each wave 64 rows x 32 cols.  ~85us dispatch
// (51us marginal compute per R9 x4-rep measurement; remainder is wave ramp).
// Probed and closed: deeper pipelining (R6 neutral), full-K panel (R10
// regressed), fusion (R12 regressed).  Do not re-tune without new counters.
// ---------------------------------------------------------------------------
__global__ __launch_bounds__(512) void gemm_qk_mfma(
    const float* __restrict__ Xu, const float* __restrict__ Xi,
    const _Float16* __restrict__ Wt_hi, const _Float16* __restrict__ Wt_lo,
    const float* __restrict__ bq, const float* __restrict__ bk,
    __half* __restrict__ QK, int U, int I)
{
    __shared__ _Float16 Ah[64][72];
    __shared__ _Float16 Al[64][72];

    const int tid  = threadIdx.x;
    const int row0 = blockIdx.x * 64;
    const int l    = tid & 63;
    const int lr   = l & 15;
    const int kc   = l >> 4;          // k-chunk 0..3
    const int n0   = (tid >> 6) * 32; // wave 0..7 -> 32-col slice
    const int NT   = U + I;

    f32x4 acc[4][2];
#pragma unroll
    for (int i = 0; i < 4; ++i)
#pragma unroll
        for (int j = 0; j < 2; ++j)
            acc[i][j] = (f32x4){0.f, 0.f, 0.f, 0.f};

    // staging role: 512 threads cover 64 rows x 64 halves; thread -> 8 floats
    const int sr = tid >> 3;          // row 0..63
    const int sk = (tid & 7) * 8;     // half-offset 0..56
    const float* Xrow = nullptr;
    {
        int gr = row0 + sr;
        if (gr < U)       Xrow = &Xu[(size_t)gr * 256];
        else if (gr < NT) Xrow = &Xi[(size_t)(gr - U) * 256];
    }

    for (int k0 = 0; k0 < 256; k0 += 64) {
        // ---- stage A tile (64 x 64 halves) as hi/lo fp16 ----
        {
            fv4 v0, v1;
            if (Xrow) {
                v0 = __builtin_nontemporal_load((const fv4*)(Xrow + k0 + sk));
                v1 = __builtin_nontemporal_load((const fv4*)(Xrow + k0 + sk + 4));
            } else {
                v0 = v1 = (fv4){0.f, 0.f, 0.f, 0.f};
            }
            float x[8] = {v0.x, v0.y, v0.z, v0.w, v1.x, v1.y, v1.z, v1.w};
            _Float16 hi[8], lo[8];
#pragma unroll
            for (int q = 0; q < 8; ++q) {
                hi[q] = (_Float16)x[q];
                lo[q] = (_Float16)(x[q] - (float)hi[q]);
            }
            *(f16x8*)&Ah[sr][sk] = *(const f16x8*)&hi[0];
            *(f16x8*)&Al[sr][sk] = *(const f16x8*)&lo[0];
        }
        __syncthreads();

#pragma unroll
        for (int kk = 0; kk < 2; ++kk) {
            const int kof = kk * 32 + kc * 8;
            f16x8 ah[4], al[4];
#pragma unroll
            for (int i = 0; i < 4; ++i) {
                ah[i] = *(const f16x8*)&Ah[i * 16 + lr][kof];
                al[i] = *(const f16x8*)&Al[i * 16 + lr][kof];
            }
#pragma unroll
            for (int j = 0; j < 2; ++j) {
                const size_t wo = (size_t)(n0 + j * 16 + lr) * 256 + k0 + kof;
                f16x8 bh = *(const f16x8*)&Wt_hi[wo];
                f16x8 bl = *(const f16x8*)&Wt_lo[wo];
#pragma unroll
                for (int i = 0; i < 4; ++i) {
                    acc[i][j] = __builtin_amdgcn_mfma_f32_16x16x32_f16(ah[i], bh, acc[i][j], 0, 0, 0);
                    acc[i][j] = __builtin_amdgcn_mfma_f32_16x16x32_f16(al[i], bh, acc[i][j], 0, 0, 0);
                    acc[i][j] = __builtin_amdgcn_mfma_f32_16x16x32_f16(ah[i], bl, acc[i][j], 0, 0, 0);
                }
            }
        }
        __syncthreads();
    }

    // ---- epilogue: bias + fp16 store ----
    float bias[2];
#pragma unroll
    for (int j = 0; j < 2; ++j) {
        int col = n0 + j * 16 + lr;
        bias[j] = (col < 128) ? bq[col] : bk[col - 128];
    }
#pragma unroll
    for (int i = 0; i < 4; ++i) {
#pragma unroll
        for (int q = 0; q < 4; ++q) {
            int gr = row0 + i * 16 + kc * 4 + q;
            if (gr < NT) {
#pragma unroll
                for (int j = 0; j < 2; ++j) {
                    int col = n0 + j * 16 + lr;
                    QK[(size_t)gr * 256 + col] = __float2half_rn(acc[i][j][q] + bias[j]);
                }
            }
        }
    }
}

// ---------------------------------------------------------------------------
// Fused BOTH-direction edge kernel, 8 lanes per edge (R4 version — measured
// at the gather-path ceiling ~3.9 TB/s / 48% HBM; R3/R4 A/B showed it
// responds to neither VALU nor MLP; R12 showed it must keep its OWN
// resource envelope (24 VGPR / 256-thr blocks).  Do not re-tune.)
// ---------------------------------------------------------------------------
__global__ __launch_bounds__(256) void edge_w_both(
    const __half* __restrict__ QK,
    const int* __restrict__ rows, const int* __restrict__ cols,
    const float* __restrict__ noise_ui, const float* __restrict__ noise_iu,
    float* __restrict__ out, double* __restrict__ seg_sumd, int U, int E)
{
    const int gtid = blockIdx.x * 256 + threadIdx.x;
    const int eid  = gtid >> 3;
    if (eid >= E) return;
    const int hl = threadIdx.x & 7;

    const int r = __builtin_nontemporal_load(&rows[eid]);
    const int c = __builtin_nontemporal_load(&cols[eid]);
    const __half* urow = QK + (size_t)r * 256;
    const __half* irow = QK + (size_t)(U + c) * 256;

    const uint4 qu0 = *(const uint4*)(urow + hl * 16);
    const uint4 qu1 = *(const uint4*)(urow + hl * 16 + 8);
    const uint4 ku0 = *(const uint4*)(urow + 128 + hl * 16);
    const uint4 ku1 = *(const uint4*)(urow + 128 + hl * 16 + 8);
    const uint4 qi0 = *(const uint4*)(irow + hl * 16);
    const uint4 qi1 = *(const uint4*)(irow + hl * 16 + 8);
    const uint4 ki0 = *(const uint4*)(irow + 128 + hl * 16);
    const uint4 ki1 = *(const uint4*)(irow + 128 + hl * 16 + 8);

    float d0 = 0.0f, d1 = 0.0f;
    {
        const half2v* a0 = (const half2v*)&qu0;
        const half2v* b0 = (const half2v*)&ki0;
        const half2v* a1 = (const half2v*)&qi0;
        const half2v* b1 = (const half2v*)&ku0;
#pragma unroll
        for (int t = 0; t < 4; ++t) {
            d0 = __builtin_amdgcn_fdot2(a0[t], b0[t], d0, false);
            d1 = __builtin_amdgcn_fdot2(a1[t], b1[t], d1, false);
        }
        const half2v* a0b = (const half2v*)&qu1;
        const half2v* b0b = (const half2v*)&ki1;
        const half2v* a1b = (const half2v*)&qi1;
        const half2v* b1b = (const half2v*)&ku1;
#pragma unroll
        for (int t = 0; t < 4; ++t) {
            d0 = __builtin_amdgcn_fdot2(a0b[t], b0b[t], d0, false);
            d1 = __builtin_amdgcn_fdot2(a1b[t], b1b[t], d1, false);
        }
    }
    d0 += __shfl_xor(d0, 4);  d1 += __shfl_xor(d1, 4);
    d0 += __shfl_xor(d0, 2);  d1 += __shfl_xor(d1, 2);
    d0 += __shfl_xor(d0, 1);  d1 += __shfl_xor(d1, 1);

    if (hl < 2) {
        const int g  = hl;                      // 0 = ui, 1 = iu
        const float d  = g ? d1 : d0;
        const float nz = g ? __builtin_nontemporal_load(&noise_iu[eid])
                           : __builtin_nontemporal_load(&noise_ui[eid]);
        const float zz = (d - __logf(-__logf(nz))) * TAU_INV;
        const int s  = g ? (U + c) : r;
        __builtin_nontemporal_store(zz, &out[(size_t)g * E + eid]);
        atomicAdd(&seg_sumd[s], exp_double(zz));
    }
}

// ---------------------------------------------------------------------------
// out = exp(z) / S[seg]  computed as  exp2(z*log2e - log2(S)).  Vectorized
// 2 elems/thread (R3/R5 form).
// ---------------------------------------------------------------------------
__global__ void edge_norm2v(float* __restrict__ z,
                            const int* __restrict__ rows, const int* __restrict__ cols,
                            const double* __restrict__ seg_sumd, int U, int E)
{
    int p = blockIdx.x * blockDim.x + threadIdx.x;
    int i = p * 2;
    if (i >= 2 * E) return;
    const bool iu  = (i >= E);
    const int base = iu ? (i - E) : i;
    const int off  = iu ? U : 0;
    const int* idx = iu ? cols : rows;
    int2 rc   = *(const int2*)&idx[base];
    float2 zz = *(const float2*)&z[i];
    float l0 = log2_of_double(seg_sumd[off + rc.x]);
    float l1 = log2_of_double(seg_sumd[off + rc.y]);
    float o0 = fast_exp2(zz.x * LOG2E - l0);
    float o1 = fast_exp2(zz.y * LOG2E - l1);
    *(float2*)&z[i] = make_float2(o0, o1);
}

__global__ void edge_norm2(float* __restrict__ z,
                           const int* __restrict__ rows, const int* __restrict__ cols,
                           const double* __restrict__ seg_sumd, int U, int E)
{
    int i = blockIdx.x * blockDim.x + threadIdx.x;
    if (i >= 2 * E) return;
    int s = (i < E) ? rows[i] : (U + cols[i - E]);
    float l = log2_of_double(seg_sumd[s]);
    z[i] = fast_exp2(z[i] * LOG2E - l);
}

// ---------------------------------------------------------------------------
extern "C" void kernel_launch(void* const* d_in, const int* in_sizes, int n_in,
                              void* d_out, int out_size, void* d_ws, size_t ws_size,
                              hipStream_t stream)
{
    const float* user_embed = (const float*)d_in[0];
    const float* item_embed = (const float*)d_in[1];
    const float* Wq = (const float*)d_in[2];
    const float* bq = (const float*)d_in[3];
    const float* Wk = (const float*)d_in[4];
    const float* bk = (const float*)d_in[5];
    const int* ui_rows    = (const int*)d_in[6];
    const int* ui_cols    = (const int*)d_in[7];
    const float* noise_ui = (const float*)d_in[8];
    const float* noise_iu = (const float*)d_in[9];

    const int H = in_sizes[3];           // 128
    const int D = in_sizes[2] / H;       // 256
    const int U = in_sizes[0] / D;       // 50000
    const int I = in_sizes[1] / D;       // 25000
    const int E = in_sizes[6];           // 1600000

    const int nseg = U + I;

    // workspace: QK fp16 (U+I)x256 | seg_sumd double | Wt_hi | Wt_lo
    char* wsc = (char*)d_ws;
    __half* QK = (__half*)wsc;          wsc += (size_t)nseg * 256 * sizeof(__half);
    double* seg_sumd = (double*)wsc;    wsc += (size_t)nseg * sizeof(double);
    _Float16* Wt_hi = (_Float16*)wsc;   wsc += (size_t)256 * 256 * sizeof(_Float16);
    _Float16* Wt_lo = (_Float16*)wsc;   wsc += (size_t)256 * 256 * sizeof(_Float16);

    float* out = (float*)d_out;         // [z_ui | z_iu] -> normalized in place

    convert_w<<<256, 256, 0, stream>>>(Wq, Wk, Wt_hi, Wt_lo, seg_sumd, nseg);

    const int gblocks = (nseg + 63) / 64;
    gemm_qk_mfma<<<gblocks, 512, 0, stream>>>(user_embed, item_embed,
                                              Wt_hi, Wt_lo, bq, bk, QK, U, I);

    const int eblocks = (int)(((long long)E * 8 + 255) / 256);
    edge_w_both<<<eblocks, 256, 0, stream>>>(QK, ui_rows, ui_cols,
                                             noise_ui, noise_iu,
                                             out, seg_sumd, U, E);

    if ((E & 1) == 0) {
        const int vblocks = (E + 255) / 256;   // E pairs cover 2E elements
        edge_norm2v<<<vblocks, 256, 0, stream>>>(out, ui_rows, ui_cols,
                                                 seg_sumd, U, E);
    } else {
        const int sblocks = (2 * E + 255) / 256;
        edge_norm2<<<sblocks, 256, 0, stream>>>(out, ui_rows, ui_cols,
                                                seg_sumd, U, E);
    }
}